// Round 10
// baseline (186.397 us; speedup 1.0000x reference)
//
#include <hip/hip_runtime.h>
#include <stdint.h>

typedef __bf16 bf16x8 __attribute__((ext_vector_type(8)));
typedef float  f32x4  __attribute__((ext_vector_type(4)));
typedef float  f32x16 __attribute__((ext_vector_type(16)));

#define QSCALE 0.18033688011112042f  /* 0.125 * log2(e) */

typedef __attribute__((address_space(1))) const void* as1cv;
typedef __attribute__((address_space(3))) void*       as3v;

__device__ __forceinline__ void gload16(const void* g, void* l) {
  __builtin_amdgcn_global_load_lds((as1cv)g, (as3v)l, 16, 0, 0);
}

__device__ __forceinline__ unsigned short f2b(float f) {
  union { float f; unsigned int u; } v; v.f = f;
  unsigned int r = v.u + 0x7fffu + ((v.u >> 16) & 1u);
  return (unsigned short)(r >> 16);
}

__device__ __forceinline__ float b2f(unsigned short s) {
  union { unsigned int u; float f; } v; v.u = (unsigned int)s << 16;
  return v.f;
}

#if __has_builtin(__builtin_amdgcn_exp2f)
__device__ __forceinline__ float fexp2(float x) { return __builtin_amdgcn_exp2f(x); }
#else
__device__ __forceinline__ float fexp2(float x) {
  float r;
  asm volatile("v_exp_f32 %0, %1\n\ts_nop 1" : "=v"(r) : "v"(x));
  return r;
}
#endif

// ---------------- dtype probe ----------------
__global__ void detect_dtype(const unsigned short* __restrict__ x, int* __restrict__ flag) {
  const int t = threadIdx.x;  // 64
  bool big = false;
  for (int i = t; i < 1024; i += 64) {
    float f = b2f(x[i]);
    if (!(fabsf(f) < 1e6f)) big = true;
  }
  if (t == 0) *flag = 0;
  __syncthreads();
  if (__any(big) && t == 0) *flag = 1;
}

// ---------------- x -> bf16 copy/convert ----------------
__global__ __launch_bounds__(256) void convert_x(const void* __restrict__ src,
                                                 unsigned short* __restrict__ dst,
                                                 const int* __restrict__ flag) {
  const int i = blockIdx.x * 256 + threadIdx.x;
  if (*flag) {
    float4 a = ((const float4*)src)[2 * i];
    float4 b = ((const float4*)src)[2 * i + 1];
    union { unsigned short o[8]; uint4 v; } u;
    u.o[0] = f2b(a.x); u.o[1] = f2b(a.y); u.o[2] = f2b(a.z); u.o[3] = f2b(a.w);
    u.o[4] = f2b(b.x); u.o[5] = f2b(b.y); u.o[6] = f2b(b.z); u.o[7] = f2b(b.w);
    ((uint4*)dst)[i] = u.v;
  } else {
    ((uint4*)dst)[i] = ((const uint4*)src)[i];
  }
}

// ---------------- merged weight transpose: z selects wq/wk/wv/wo ----------------
__global__ __launch_bounds__(256) void transpose_w4(const void* __restrict__ wq,
                                                    const void* __restrict__ wk,
                                                    const void* __restrict__ wv,
                                                    const void* __restrict__ wo,
                                                    unsigned short* __restrict__ WT,
                                                    unsigned short* __restrict__ WOT,
                                                    const int* __restrict__ flag) {
  const int z = blockIdx.z;
  const void* src;
  unsigned short* dst;
  int C;
  const int R = 2048;
  if (z == 0)      { src = wq; dst = WT;                            C = 2048; }
  else if (z == 1) { src = wk; dst = WT + (size_t)2048 * 2048;      C = 512;  }
  else if (z == 2) { src = wv; dst = WT + (size_t)2560 * 2048;      C = 512;  }
  else             { src = wo; dst = WOT;                           C = 2048; }
  if ((int)blockIdx.x * 64 >= C) return;

  __shared__ unsigned short tile[64][72];
  const int t = threadIdx.x;
  const int r = t >> 2;
  const int c0 = (t & 3) << 4;
  const int gr = blockIdx.y * 64 + r;
  const int gc = blockIdx.x * 64 + c0;
  if (*flag) {
    const float* s = (const float*)src + (size_t)gr * C + gc;
#pragma unroll
    for (int j = 0; j < 16; j += 4) {
      float4 v = *(const float4*)(s + j);
      tile[r][c0 + j + 0] = f2b(v.x);
      tile[r][c0 + j + 1] = f2b(v.y);
      tile[r][c0 + j + 2] = f2b(v.z);
      tile[r][c0 + j + 3] = f2b(v.w);
    }
  } else {
    const unsigned short* s = (const unsigned short*)src + (size_t)gr * C + gc;
    *(uint4*)&tile[r][c0]     = *(const uint4*)s;
    *(uint4*)&tile[r][c0 + 8] = *(const uint4*)(s + 8);
  }
  __syncthreads();
  const int c    = t >> 2;
  const int rblk = (t & 3) << 4;
  union { unsigned short o[16]; uint4 v[2]; } u;
#pragma unroll
  for (int j = 0; j < 16; ++j) u.o[j] = tile[rblk + j][c];
  unsigned short* d = dst + (size_t)(blockIdx.x * 64 + c) * R + blockIdx.y * 64 + rblk;
  *(uint4*)d       = u.v[0];
  *(uint4*)(d + 8) = u.v[1];
}

// ---------------- 256^2 8-wave GEMM with counted vmcnt (T3+T4): QKV projection ----------------
// C[M][N] = A[M][K] @ Bt[N][K]^T. BM=BN=256, BK=64, 512 threads (8 waves, 2Mx4N).
// 2-buffer LDS (128KB), raw s_barrier + s_waitcnt vmcnt(8) — prefetch never drained to 0.
// V columns (n0 >= 2560) written directly as VT (fused transpose).
__global__ __launch_bounds__(512, 2) void gemm_qkv8(const unsigned short* __restrict__ A,
                                                    const unsigned short* __restrict__ Bt,
                                                    void* __restrict__ Cv,
                                                    unsigned short* __restrict__ vtout,
                                                    int M, int N, int K, int scale_cols,
                                                    const int* __restrict__ f32flag) {
  __shared__ unsigned short As[2][256 * 64];
  __shared__ unsigned short Bs[2][256 * 64];
  const int t = threadIdx.x;            // 0..511
  const int lane = t & 63;
  const int wave = t >> 6;
  const int wm = wave >> 2, wn = wave & 3;   // per-wave output 128x64
  int bx, by;
  {
    const int nx = (int)gridDim.x;
    const int nwg = nx * (int)gridDim.y;   // 192, %8==0
    const int wg = (int)blockIdx.y * nx + (int)blockIdx.x;
    const int cpx = nwg >> 3;
    const int swz = (wg & 7) * cpx + (wg >> 3);
    bx = swz % nx; by = swz / nx;
  }
  const int m0 = by * 256, n0 = bx * 256;
  const int fr = lane & 15;
  const int kb = (lane >> 4) << 4;

  // staging: 4 x 16B per operand per K-tile per thread (256 rows x 128B)
  int rowS[4], dofS[4], scS[4];
#pragma unroll
  for (int i = 0; i < 4; ++i) {
    int off = i * 8192 + t * 16;
    dofS[i] = off;
    rowS[i] = off >> 7;
    scS[i]  = (off & 127) ^ ((rowS[i] & 7) << 4);
  }
  const char* pA[4];
  const char* pB[4];
#pragma unroll
  for (int i = 0; i < 4; ++i) {
    pA[i] = (const char*)(A  + (size_t)(m0 + rowS[i]) * K) + scS[i];
    pB[i] = (const char*)(Bt + (size_t)(n0 + rowS[i]) * K) + scS[i];
  }

  f32x4 acc[8][4] = {};
  const int NT = K >> 6;   // 32

  // prologue: stage K-tile 0 into buf 0 (8 loads/thread)
#pragma unroll
  for (int i = 0; i < 4; ++i) {
    gload16(pA[i], (char*)As[0] + dofS[i]);
    gload16(pB[i], (char*)Bs[0] + dofS[i]);
  }

  for (int kt = 0; kt < NT; ++kt) {
    // stage kt+1 into buf^1 (last read at kt-1, separated by B2 barrier)
    if (kt + 1 < NT) {
      const int kby = (kt + 1) * 128;
      const int bsel = (kt + 1) & 1;
#pragma unroll
      for (int i = 0; i < 4; ++i) {
        gload16(pA[i] + kby, (char*)As[bsel] + dofS[i]);
        gload16(pB[i] + kby, (char*)Bs[bsel] + dofS[i]);
      }
      asm volatile("s_waitcnt vmcnt(8)" ::: "memory");   // kt's 8 done; fresh 8 stay in flight
    } else {
      asm volatile("s_waitcnt vmcnt(0)" ::: "memory");
    }
    __builtin_amdgcn_s_barrier();          // B1: kt data resident for all waves
    __builtin_amdgcn_sched_barrier(0);
    const char* Ab = (const char*)As[kt & 1];
    const char* Bb = (const char*)Bs[kt & 1];
#pragma unroll
    for (int ks = 0; ks < 2; ++ks) {
      bf16x8 af[8], bfv[4];
#pragma unroll
      for (int i = 0; i < 8; ++i) {
        const int ra = wm * 128 + i * 16 + fr;
        af[i] = *(const bf16x8*)(Ab + ra * 128 + ((ks * 64 + kb) ^ ((ra & 7) << 4)));
      }
#pragma unroll
      for (int j = 0; j < 4; ++j) {
        const int rb = wn * 64 + j * 16 + fr;
        bfv[j] = *(const bf16x8*)(Bb + rb * 128 + ((ks * 64 + kb) ^ ((rb & 7) << 4)));
      }
      __builtin_amdgcn_s_setprio(1);
#pragma unroll
      for (int i = 0; i < 8; ++i)
#pragma unroll
        for (int j = 0; j < 4; ++j)
          acc[i][j] = __builtin_amdgcn_mfma_f32_16x16x32_bf16(af[i], bfv[j], acc[i][j], 0, 0, 0);
      __builtin_amdgcn_s_setprio(0);
    }
    __builtin_amdgcn_s_barrier();          // B2: all waves done reading buf[kt&1]
    __builtin_amdgcn_sched_barrier(0);
  }

  const int cm0 = m0 + wm * 128 + ((lane >> 4) << 2);
  const int cn0 = n0 + wn * 64 + fr;
  if (vtout && n0 >= 2560) {
    const int bb = m0 >> 11;
#pragma unroll
    for (int i = 0; i < 8; ++i) {
      const int s0 = cm0 + i * 16;
#pragma unroll
      for (int j = 0; j < 4; ++j) {
        const int d = cn0 + j * 16 - 2560;
        uint2 pr;
        pr.x = (unsigned int)f2b(acc[i][j][0]) | ((unsigned int)f2b(acc[i][j][1]) << 16);
        pr.y = (unsigned int)f2b(acc[i][j][2]) | ((unsigned int)f2b(acc[i][j][3]) << 16);
        *(uint2*)(vtout + (size_t)(bb * 512 + d) * 2048 + (s0 & 2047)) = pr;
      }
    }
    return;
  }
  const bool of32 = f32flag && (*f32flag != 0);
  if (of32) {
    float* C = (float*)Cv;
#pragma unroll
    for (int i = 0; i < 8; ++i)
#pragma unroll
      for (int j = 0; j < 4; ++j) {
        float sc = (cn0 + j * 16 < scale_cols) ? QSCALE : 1.0f;
#pragma unroll
        for (int r = 0; r < 4; ++r)
          C[(size_t)(cm0 + i * 16 + r) * N + (cn0 + j * 16)] = acc[i][j][r] * sc;
      }
  } else {
    unsigned short* C = (unsigned short*)Cv;
#pragma unroll
    for (int i = 0; i < 8; ++i)
#pragma unroll
      for (int j = 0; j < 4; ++j) {
        float sc = (cn0 + j * 16 < scale_cols) ? QSCALE : 1.0f;
#pragma unroll
        for (int r = 0; r < 4; ++r)
          C[(size_t)(cm0 + i * 16 + r) * N + (cn0 + j * 16)] = f2b(acc[i][j][r] * sc);
      }
  }
}

// ---------------- bf16 GEMM v2 (128^2, proven): out-projection ----------------
__global__ __launch_bounds__(256) void gemm_bt2(const unsigned short* __restrict__ A,
                                                const unsigned short* __restrict__ Bt,
                                                void* __restrict__ Cv,
                                                unsigned short* __restrict__ vtout,
                                                int M, int N, int K, int scale_cols,
                                                const int* __restrict__ f32flag) {
  __shared__ unsigned short As[2][128 * 64];
  __shared__ unsigned short Bs[2][128 * 64];
  const int t = threadIdx.x;
  const int lane = t & 63;
  const int wave = t >> 6;
  const int wm = wave >> 1, wn = wave & 1;
  int bx, by;
  {
    const int nx = (int)gridDim.x;
    const int nwg = nx * (int)gridDim.y;
    const int wg = (int)blockIdx.y * nx + (int)blockIdx.x;
    const int cpx = nwg >> 3;
    const int swz = (wg & 7) * cpx + (wg >> 3);
    bx = swz % nx; by = swz / nx;
  }
  const int m0 = by * 128, n0 = bx * 128;
  const int fr = lane & 15;
  const int kb = (lane >> 4) << 4;

  int rowS[4], dofS[4], scS[4];
#pragma unroll
  for (int i = 0; i < 4; ++i) {
    int off = i * 4096 + t * 16;
    dofS[i] = off;
    rowS[i] = off >> 7;
    scS[i]  = (off & 127) ^ ((rowS[i] & 7) << 4);
  }
  const char* pA[4];
  const char* pB[4];
#pragma unroll
  for (int i = 0; i < 4; ++i) {
    pA[i] = (const char*)(A  + (size_t)(m0 + rowS[i]) * K) + scS[i];
    pB[i] = (const char*)(Bt + (size_t)(n0 + rowS[i]) * K) + scS[i];
  }

  f32x4 acc[4][4] = {};
  const int NT = K >> 6;

#pragma unroll
  for (int i = 0; i < 4; ++i) {
    gload16(pA[i], (char*)As[0] + dofS[i]);
    gload16(pB[i], (char*)Bs[0] + dofS[i]);
  }
  __syncthreads();

  for (int kt = 0; kt < NT; ++kt) {
    if (kt + 1 < NT) {
      const int kby = (kt + 1) * 128;
      const int bsel = (kt + 1) & 1;
#pragma unroll
      for (int i = 0; i < 4; ++i) {
        gload16(pA[i] + kby, (char*)As[bsel] + dofS[i]);
        gload16(pB[i] + kby, (char*)Bs[bsel] + dofS[i]);
      }
    }
    const char* Ab = (const char*)As[kt & 1];
    const char* Bb = (const char*)Bs[kt & 1];
#pragma unroll
    for (int ks = 0; ks < 2; ++ks) {
      bf16x8 af[4], bfv[4];
#pragma unroll
      for (int i = 0; i < 4; ++i) {
        const int ra = wm * 64 + i * 16 + fr;
        af[i] = *(const bf16x8*)(Ab + ra * 128 + ((ks * 64 + kb) ^ ((ra & 7) << 4)));
        const int rb = wn * 64 + i * 16 + fr;
        bfv[i] = *(const bf16x8*)(Bb + rb * 128 + ((ks * 64 + kb) ^ ((rb & 7) << 4)));
      }
      __builtin_amdgcn_s_setprio(1);
#pragma unroll
      for (int i = 0; i < 4; ++i)
#pragma unroll
        for (int j = 0; j < 4; ++j)
          acc[i][j] = __builtin_amdgcn_mfma_f32_16x16x32_bf16(af[i], bfv[j], acc[i][j], 0, 0, 0);
      __builtin_amdgcn_s_setprio(0);
    }
    __syncthreads();
  }

  const int cm0 = m0 + wm * 64 + ((lane >> 4) << 2);
  const int cn0 = n0 + wn * 64 + fr;
  if (vtout && n0 >= 2560) {
    const int bb = m0 >> 11;
#pragma unroll
    for (int i = 0; i < 4; ++i) {
      const int s0 = cm0 + i * 16;
#pragma unroll
      for (int j = 0; j < 4; ++j) {
        const int d = cn0 + j * 16 - 2560;
        uint2 pr;
        pr.x = (unsigned int)f2b(acc[i][j][0]) | ((unsigned int)f2b(acc[i][j][1]) << 16);
        pr.y = (unsigned int)f2b(acc[i][j][2]) | ((unsigned int)f2b(acc[i][j][3]) << 16);
        *(uint2*)(vtout + (size_t)(bb * 512 + d) * 2048 + (s0 & 2047)) = pr;
      }
    }
    return;
  }
  const bool of32 = f32flag && (*f32flag != 0);
  if (of32) {
    float* C = (float*)Cv;
#pragma unroll
    for (int i = 0; i < 4; ++i)
#pragma unroll
      for (int j = 0; j < 4; ++j) {
        float sc = (cn0 + j * 16 < scale_cols) ? QSCALE : 1.0f;
#pragma unroll
        for (int r = 0; r < 4; ++r)
          C[(size_t)(cm0 + i * 16 + r) * N + (cn0 + j * 16)] = acc[i][j][r] * sc;
      }
  } else {
    unsigned short* C = (unsigned short*)Cv;
#pragma unroll
    for (int i = 0; i < 4; ++i)
#pragma unroll
      for (int j = 0; j < 4; ++j) {
        float sc = (cn0 + j * 16 < scale_cols) ? QSCALE : 1.0f;
#pragma unroll
        for (int r = 0; r < 4; ++r)
          C[(size_t)(cm0 + i * 16 + r) * N + (cn0 + j * 16)] = f2b(acc[i][j][r] * sc);
      }
  }
}

// ---------------- causal GQA flash attention v7: 1024 blocks, 4-round balanced qt ----------------
__global__ __launch_bounds__(256, 4) void attn_fwd7(const unsigned short* __restrict__ qkv,
                                                    const unsigned short* __restrict__ vt,
                                                    unsigned short* __restrict__ ob) {
  __shared__ unsigned short Ks[2][64 * 64];
  __shared__ unsigned short Vs[2][64 * 64];
  const int t = threadIdx.x, lane = t & 63, w = t >> 6;
  const int half = lane >> 5, q32 = lane & 31;
  const int lin = (int)blockIdx.x;
  const int rr = lin >> 8;
  const int k  = (lin & 255) >> 4;
  const int gb = lin & 15;
  const int g = gb & 7, b = gb >> 3;
  const int qt = (rr == 0) ? 63 - k : (rr == 1) ? 32 + k : (rr == 2) ? 31 - k : k;
  const int h = g * 4 + w;
  const size_t bS = (size_t)b * 2048;
  const size_t vtb = ((size_t)((b << 3) + g)) * 64;
  const int nkt = (qt >> 1) + 1;
  const int q_glob = qt * 32 + q32;

  int rowS[2], dofS[2], cbS[2];
#pragma unroll
  for (int i = 0; i < 2; ++i) {
    int off = i * 4096 + t * 16;
    dofS[i] = off;
    rowS[i] = off >> 7;
    cbS[i]  = (off & 127) ^ ((rowS[i] & 7) << 4);
  }

  bf16x8 qf[4];
  {
    const unsigned short* qrow = qkv + (bS + q_glob) * 3072 + h * 64 + half * 8;
#pragma unroll
    for (int c = 0; c < 4; ++c) qf[c] = *(const bf16x8*)(qrow + 16 * c);
  }
  const unsigned short* kp[2];
  const unsigned short* vp[2];
#pragma unroll
  for (int i = 0; i < 2; ++i) {
    kp[i] = qkv + (bS + rowS[i]) * 3072 + 2048 + g * 64 + (cbS[i] >> 1);
    vp[i] = vt + (vtb + rowS[i]) * 2048 + (cbS[i] >> 1);
  }
  f32x16 Ot0 = {}, Ot1 = {};
  float m_run = -1e30f, l_run = 0.f;

#pragma unroll
  for (int i = 0; i < 2; ++i) {
    gload16(kp[i], (char*)Ks[0] + dofS[i]);
    gload16(vp[i], (char*)Vs[0] + dofS[i]);
    kp[i] += 64 * 3072;
    vp[i] += 64;
  }
  int cur = 0;
  for (int kt = 0; kt < nkt; ++kt) {
    __syncthreads();
    if (kt + 1 < nkt) {
#pragma unroll
      for (int i = 0; i < 2; ++i) {
        gload16(kp[i], (char*)Ks[cur ^ 1] + dofS[i]);
        gload16(vp[i], (char*)Vs[cur ^ 1] + dofS[i]);
        kp[i] += 64 * 3072;
        vp[i] += 64;
      }
    }
    const char* Kb = (const char*)Ks[cur];
    const char* Vb = (const char*)Vs[cur];
    const int sk1 = 2 * kt + 1;
    const bool do1 = (sk1 <= qt);

    f32x16 s0 = {}, s1 = {};
    {
      const int kr0 = q32;
      const int ksw0 = (kr0 & 7) << 4;
      bf16x8 ka0 = *(const bf16x8*)(Kb + kr0 * 128 + ((16 * half) ^ ksw0));
      bf16x8 ka1 = *(const bf16x8*)(Kb + kr0 * 128 + ((32 + 16 * half) ^ ksw0));
      bf16x8 ka2 = *(const bf16x8*)(Kb + kr0 * 128 + ((64 + 16 * half) ^ ksw0));
      bf16x8 ka3 = *(const bf16x8*)(Kb + kr0 * 128 + ((96 + 16 * half) ^ ksw0));
      __builtin_amdgcn_s_setprio(1);
      s0 = __builtin_amdgcn_mfma_f32_32x32x16_bf16(ka0, qf[0], s0, 0, 0, 0);
      s0 = __builtin_amdgcn_mfma_f32_32x32x16_bf16(ka1, qf[1], s0, 0, 0, 0);
      s0 = __builtin_amdgcn_mfma_f32_32x32x16_bf16(ka2, qf[2], s0, 0, 0, 0);
      s0 = __builtin_amdgcn_mfma_f32_32x32x16_bf16(ka3, qf[3], s0, 0, 0, 0);
      __builtin_amdgcn_s_setprio(0);
    }
    if (do1) {
      const int kr1 = 32 + q32;
      const int ksw1 = (kr1 & 7) << 4;
      bf16x8 kb0 = *(const bf16x8*)(Kb + kr1 * 128 + ((16 * half) ^ ksw1));
      bf16x8 kb1 = *(const bf16x8*)(Kb + kr1 * 128 + ((32 + 16 * half) ^ ksw1));
      bf16x8 kb2 = *(const bf16x8*)(Kb + kr1 * 128 + ((64 + 16 * half) ^ ksw1));
      bf16x8 kb3 = *(const bf16x8*)(Kb + kr1 * 128 + ((96 + 16 * half) ^ ksw1));
      __builtin_amdgcn_s_setprio(1);
      s1 = __builtin_amdgcn_mfma_f32_32x32x16_bf16(kb0, qf[0], s1, 0, 0, 0);
      s1 = __builtin_amdgcn_mfma_f32_32x32x16_bf16(kb1, qf[1], s1, 0, 0, 0);
      s1 = __builtin_amdgcn_mfma_f32_32x32x16_bf16(kb2, qf[2], s1, 0, 0, 0);
      s1 = __builtin_amdgcn_mfma_f32_32x32x16_bf16(kb3, qf[3], s1, 0, 0, 0);
      __builtin_amdgcn_s_setprio(0);
    }
    const int qrel = q32 - 4 * half;
    if (2 * kt == qt) {
#pragma unroll
      for (int r = 0; r < 16; ++r) {
        const int pat = (r & 3) + 8 * (r >> 2);
        if (pat > qrel) s0[r] = -1e30f;
      }
    }
    if (do1 && sk1 == qt) {
#pragma unroll
      for (int r = 0; r < 16; ++r) {
        const int pat = (r & 3) + 8 * (r >> 2);
        if (pat > qrel) s1[r] = -1e30f;
      }
    }
    float tm[8];
#pragma unroll
    for (int r = 0; r < 8; ++r) tm[r] = fmaxf(s0[r], s0[r + 8]);
    if (do1) {
#pragma unroll
      for (int r = 0; r < 8; ++r) tm[r] = fmaxf(tm[r], fmaxf(s1[r], s1[r + 8]));
    }
#pragma unroll
    for (int r = 0; r < 4; ++r) tm[r] = fmaxf(tm[r], tm[r + 4]);
    float pm = fmaxf(fmaxf(tm[0], tm[1]), fmaxf(tm[2], tm[3]));
    pm = fmaxf(pm, __shfl_xor(pm, 32, 64));
    if (!__all(pm - m_run <= 8.f)) {
      const float mn = fmaxf(m_run, pm);
      const float corr = fexp2(m_run - mn);
      m_run = mn;
      l_run *= corr;
#pragma unroll
      for (int r = 0; r < 16; ++r) { Ot0[r] *= corr; Ot1[r] *= corr; }
    }
    float ts[8];
#pragma unroll
    for (int r = 0; r < 16; ++r) s0[r] = fexp2(s0[r] - m_run);
    if (do1) {
#pragma unroll
      for (int r = 0; r < 16; ++r) s1[r] = fexp2(s1[r] - m_run);
    }
#pragma unroll
    for (int r = 0; r < 8; ++r) ts[r] = s0[r] + s0[r + 8];
    if (do1) {
#pragma unroll
      for (int r = 0; r < 8; ++r) ts[r] += s1[r] + s1[r + 8];
    }
#pragma unroll
    for (int r = 0; r < 4; ++r) ts[r] += ts[r + 4];
    float rs = (ts[0] + ts[1]) + (ts[2] + ts[3]);
    rs += __shfl_xor(rs, 32, 64);
    l_run += rs;
    bf16x8 pf0, pf1, pf2, pf3;
    {
      unsigned int a01, a23, a45, a67;
      asm("v_cvt_pk_bf16_f32 %0, %1, %2" : "=v"(a01) : "v"(s0[0]), "v"(s0[1]));
      asm("v_cvt_pk_bf16_f32 %0, %1, %2" : "=v"(a23) : "v"(s0[2]), "v"(s0[3]));
      asm("v_cvt_pk_bf16_f32 %0, %1, %2" : "=v"(a45) : "v"(s0[4]), "v"(s0[5]));
      asm("v_cvt_pk_bf16_f32 %0, %1, %2" : "=v"(a67) : "v"(s0[6]), "v"(s0[7]));
      asm("v_permlane32_swap_b32 %0, %1" : "+v"(a01), "+v"(a45));
      asm("v_permlane32_swap_b32 %0, %1" : "+v"(a23), "+v"(a67));
      union { unsigned int u[4]; bf16x8 v; } fu;
      fu.u[0] = a01; fu.u[1] = a23; fu.u[2] = a45; fu.u[3] = a67;
      pf0 = fu.v;
      asm("v_cvt_pk_bf16_f32 %0, %1, %2" : "=v"(a01) : "v"(s0[8]),  "v"(s0[9]));
      asm("v_cvt_pk_bf16_f32 %0, %1, %2" : "=v"(a23) : "v"(s0[10]), "v"(s0[11]));
      asm("v_cvt_pk_bf16_f32 %0, %1, %2" : "=v"(a45) : "v"(s0[12]), "v"(s0[13]));
      asm("v_cvt_pk_bf16_f32 %0, %1, %2" : "=v"(a67) : "v"(s0[14]), "v"(s0[15]));
      asm("v_permlane32_swap_b32 %0, %1" : "+v"(a01), "+v"(a45));
      asm("v_permlane32_swap_b32 %0, %1" : "+v"(a23), "+v"(a67));
      fu.u[0] = a01; fu.u[1] = a23; fu.u[2] = a45; fu.u[3] = a67;
      pf1 = fu.v;
    }
    if (do1) {
      unsigned int a01, a23, a45, a67;
      asm("v_cvt_pk_bf16_f32 %0, %1, %2" : "=v"(a01) : "v"(s1[0]), "v"(s1[1]));
      asm("v_cvt_pk_bf16_f32 %0, %1, %2" : "=v"(a23) : "v"(s1[2]), "v"(s1[3]));
      asm("v_cvt_pk_bf16_f32 %0, %1, %2" : "=v"(a45) : "v"(s1[4]), "v"(s1[5]));
      asm("v_cvt_pk_bf16_f32 %0, %1, %2" : "=v"(a67) : "v"(s1[6]), "v"(s1[7]));
      asm("v_permlane32_swap_b32 %0, %1" : "+v"(a01), "+v"(a45));
      asm("v_permlane32_swap_b32 %0, %1" : "+v"(a23), "+v"(a67));
      union { unsigned int u[4]; bf16x8 v; } fu;
      fu.u[0] = a01; fu.u[1] = a23; fu.u[2] = a45; fu.u[3] = a67;
      pf2 = fu.v;
      asm("v_cvt_pk_bf16_f32 %0, %1, %2" : "=v"(a01) : "v"(s1[8]),  "v"(s1[9]));
      asm("v_cvt_pk_bf16_f32 %0, %1, %2" : "=v"(a23) : "v"(s1[10]), "v"(s1[11]));
      asm("v_cvt_pk_bf16_f32 %0, %1, %2" : "=v"(a45) : "v"(s1[12]), "v"(s1[13]));
      asm("v_cvt_pk_bf16_f32 %0, %1, %2" : "=v"(a67) : "v"(s1[14]), "v"(s1[15]));
      asm("v_permlane32_swap_b32 %0, %1" : "+v"(a01), "+v"(a45));
      asm("v_permlane32_swap_b32 %0, %1" : "+v"(a23), "+v"(a67));
      fu.u[0] = a01; fu.u[1] = a23; fu.u[2] = a45; fu.u[3] = a67;
      pf3 = fu.v;
    }
    const int vsw0 = (q32 & 7) << 4;
    {
      const int cbase = 16 * half;
      bf16x8 vf00 = *(const bf16x8*)(Vb + q32 * 128 + (cbase ^ vsw0));
      bf16x8 vf01 = *(const bf16x8*)(Vb + q32 * 128 + ((cbase + 32) ^ vsw0));
      bf16x8 vf10 = *(const bf16x8*)(Vb + (32 + q32) * 128 + (cbase ^ vsw0));
      bf16x8 vf11 = *(const bf16x8*)(Vb + (32 + q32) * 128 + ((cbase + 32) ^ vsw0));
      __builtin_amdgcn_s_setprio(1);
      Ot0 = __builtin_amdgcn_mfma_f32_32x32x16_bf16(vf00, pf0, Ot0, 0, 0, 0);
      Ot0 = __builtin_amdgcn_mfma_f32_32x32x16_bf16(vf01, pf1, Ot0, 0, 0, 0);
      Ot1 = __builtin_amdgcn_mfma_f32_32x32x16_bf16(vf10, pf0, Ot1, 0, 0, 0);
      Ot1 = __builtin_amdgcn_mfma_f32_32x32x16_bf16(vf11, pf1, Ot1, 0, 0, 0);
      __builtin_amdgcn_s_setprio(0);
    }
    if (do1) {
      const int cbase = 64 + 16 * half;
      bf16x8 vf00 = *(const bf16x8*)(Vb + q32 * 128 + (cbase ^ vsw0));
      bf16x8 vf01 = *(const bf16x8*)(Vb + q32 * 128 + ((cbase + 32) ^ vsw0));
      bf16x8 vf10 = *(const bf16x8*)(Vb + (32 + q32) * 128 + (cbase ^ vsw0));
      bf16x8 vf11 = *(const bf16x8*)(Vb + (32 + q32) * 128 + ((cbase + 32) ^ vsw0));
      __builtin_amdgcn_s_setprio(1);
      Ot0 = __builtin_amdgcn_mfma_f32_32x32x16_bf16(vf00, pf2, Ot0, 0, 0, 0);
      Ot0 = __builtin_amdgcn_mfma_f32_32x32x16_bf16(vf01, pf3, Ot0, 0, 0, 0);
      Ot1 = __builtin_amdgcn_mfma_f32_32x32x16_bf16(vf10, pf2, Ot1, 0, 0, 0);
      Ot1 = __builtin_amdgcn_mfma_f32_32x32x16_bf16(vf11, pf3, Ot1, 0, 0, 0);
      __builtin_amdgcn_s_setprio(0);
    }
    cur ^= 1;
  }
  const float inv = 1.f / l_run;
  unsigned short* orow = ob + (bS + q_glob) * 2048 + h * 64;
#pragma unroll
  for (int j = 0; j < 4; ++j) {
    uint2 pr;
    pr.x = (unsigned int)f2b(Ot0[4 * j + 0] * inv) | ((unsigned int)f2b(Ot0[4 * j + 1] * inv) << 16);
    pr.y = (unsigned int)f2b(Ot0[4 * j + 2] * inv) | ((unsigned int)f2b(Ot0[4 * j + 3] * inv) << 16);
    *(uint2*)(orow + 8 * j + 4 * half) = pr;
    uint2 pr2;
    pr2.x = (unsigned int)f2b(Ot1[4 * j + 0] * inv) | ((unsigned int)f2b(Ot1[4 * j + 1] * inv) << 16);
    pr2.y = (unsigned int)f2b(Ot1[4 * j + 2] * inv) | ((unsigned int)f2b(Ot1[4 * j + 3] * inv) << 16);
    *(uint2*)(orow + 32 + 8 * j + 4 * half) = pr2;
  }
}

extern "C" void kernel_launch(void* const* d_in, const int* in_sizes, int n_in,
                              void* d_out, int out_size, void* d_ws, size_t ws_size,
                              hipStream_t stream) {
  (void)in_sizes; (void)n_in; (void)out_size; (void)ws_size;
  const void* x  = d_in[0];
  const void* wq = d_in[1];
  const void* wk = d_in[2];
  const void* wv = d_in[3];
  const void* wo = d_in[4];
  unsigned short* ws = (unsigned short*)d_ws;

  int* FLAG = (int*)ws;
  unsigned short* WT  = ws + 128;
  unsigned short* WOT = WT  + (size_t)3072 * 2048;
  unsigned short* QKV = WOT + (size_t)2048 * 2048;
  unsigned short* VT  = QKV + (size_t)4096 * 3072;
  unsigned short* OB  = VT  + (size_t)16 * 64 * 2048;
  unsigned short* XB  = OB;  // x-as-bf16 (disjoint lifetime vs OB)

  detect_dtype<<<1, 64, 0, stream>>>((const unsigned short*)x, FLAG);
  transpose_w4<<<dim3(32, 32, 4), 256, 0, stream>>>(wq, wk, wv, wo, WT, WOT, FLAG);
  convert_x<<<4096, 256, 0, stream>>>(x, XB, FLAG);

  // QKV projection (256^2 counted-vmcnt kernel); V columns written directly as VT
  gemm_qkv8<<<dim3(12, 16), 512, 0, stream>>>(XB, WT, QKV, VT, 4096, 3072, 2048, 2048, nullptr);
  attn_fwd7<<<dim3(1024), 256, 0, stream>>>(QKV, VT, OB);
  gemm_bt2<<<dim3(16, 32), 256, 0, stream>>>(OB, WOT, d_out, nullptr, 4096, 2048, 2048, 0, FLAG);
}

// Round 11
// 174.635 us; speedup vs baseline: 1.0674x; 1.0674x over previous
//
#include <hip/hip_runtime.h>
#include <stdint.h>

typedef __bf16 bf16x8 __attribute__((ext_vector_type(8)));
typedef float  f32x4  __attribute__((ext_vector_type(4)));
typedef float  f32x16 __attribute__((ext_vector_type(16)));

#define QSCALE 0.18033688011112042f  /* 0.125 * log2(e) */

typedef __attribute__((address_space(1))) const void* as1cv;
typedef __attribute__((address_space(3))) void*       as3v;

__device__ __forceinline__ void gload16(const void* g, void* l) {
  __builtin_amdgcn_global_load_lds((as1cv)g, (as3v)l, 16, 0, 0);
}

__device__ __forceinline__ unsigned short f2b(float f) {
  union { float f; unsigned int u; } v; v.f = f;
  unsigned int r = v.u + 0x7fffu + ((v.u >> 16) & 1u);
  return (unsigned short)(r >> 16);
}

__device__ __forceinline__ float b2f(unsigned short s) {
  union { unsigned int u; float f; } v; v.u = (unsigned int)s << 16;
  return v.f;
}

#if __has_builtin(__builtin_amdgcn_exp2f)
__device__ __forceinline__ float fexp2(float x) { return __builtin_amdgcn_exp2f(x); }
#else
__device__ __forceinline__ float fexp2(float x) {
  float r;
  asm volatile("v_exp_f32 %0, %1\n\ts_nop 1" : "=v"(r) : "v"(x));
  return r;
}
#endif

// ---------------- dtype probe ----------------
__global__ void detect_dtype(const unsigned short* __restrict__ x, int* __restrict__ flag) {
  const int t = threadIdx.x;  // 64
  bool big = false;
  for (int i = t; i < 1024; i += 64) {
    float f = b2f(x[i]);
    if (!(fabsf(f) < 1e6f)) big = true;
  }
  if (t == 0) *flag = 0;
  __syncthreads();
  if (__any(big) && t == 0) *flag = 1;
}

// ---------------- x -> bf16 copy/convert ----------------
__global__ __launch_bounds__(256) void convert_x(const void* __restrict__ src,
                                                 unsigned short* __restrict__ dst,
                                                 const int* __restrict__ flag) {
  const int i = blockIdx.x * 256 + threadIdx.x;
  if (*flag) {
    float4 a = ((const float4*)src)[2 * i];
    float4 b = ((const float4*)src)[2 * i + 1];
    union { unsigned short o[8]; uint4 v; } u;
    u.o[0] = f2b(a.x); u.o[1] = f2b(a.y); u.o[2] = f2b(a.z); u.o[3] = f2b(a.w);
    u.o[4] = f2b(b.x); u.o[5] = f2b(b.y); u.o[6] = f2b(b.z); u.o[7] = f2b(b.w);
    ((uint4*)dst)[i] = u.v;
  } else {
    ((uint4*)dst)[i] = ((const uint4*)src)[i];
  }
}

// ---------------- merged weight transpose: z selects wq/wk/wv/wo ----------------
__global__ __launch_bounds__(256) void transpose_w4(const void* __restrict__ wq,
                                                    const void* __restrict__ wk,
                                                    const void* __restrict__ wv,
                                                    const void* __restrict__ wo,
                                                    unsigned short* __restrict__ WT,
                                                    unsigned short* __restrict__ WOT,
                                                    const int* __restrict__ flag) {
  const int z = blockIdx.z;
  const void* src;
  unsigned short* dst;
  int C;
  const int R = 2048;
  if (z == 0)      { src = wq; dst = WT;                            C = 2048; }
  else if (z == 1) { src = wk; dst = WT + (size_t)2048 * 2048;      C = 512;  }
  else if (z == 2) { src = wv; dst = WT + (size_t)2560 * 2048;      C = 512;  }
  else             { src = wo; dst = WOT;                           C = 2048; }
  if ((int)blockIdx.x * 64 >= C) return;

  __shared__ unsigned short tile[64][72];
  const int t = threadIdx.x;
  const int r = t >> 2;
  const int c0 = (t & 3) << 4;
  const int gr = blockIdx.y * 64 + r;
  const int gc = blockIdx.x * 64 + c0;
  if (*flag) {
    const float* s = (const float*)src + (size_t)gr * C + gc;
#pragma unroll
    for (int j = 0; j < 16; j += 4) {
      float4 v = *(const float4*)(s + j);
      tile[r][c0 + j + 0] = f2b(v.x);
      tile[r][c0 + j + 1] = f2b(v.y);
      tile[r][c0 + j + 2] = f2b(v.z);
      tile[r][c0 + j + 3] = f2b(v.w);
    }
  } else {
    const unsigned short* s = (const unsigned short*)src + (size_t)gr * C + gc;
    *(uint4*)&tile[r][c0]     = *(const uint4*)s;
    *(uint4*)&tile[r][c0 + 8] = *(const uint4*)(s + 8);
  }
  __syncthreads();
  const int c    = t >> 2;
  const int rblk = (t & 3) << 4;
  union { unsigned short o[16]; uint4 v[2]; } u;
#pragma unroll
  for (int j = 0; j < 16; ++j) u.o[j] = tile[rblk + j][c];
  unsigned short* d = dst + (size_t)(blockIdx.x * 64 + c) * R + blockIdx.y * 64 + rblk;
  *(uint4*)d       = u.v[0];
  *(uint4*)(d + 8) = u.v[1];
}

// ---------------- bf16 GEMM v2: 128^2, BK=64, dbuf, 2 blocks/CU (proven) ----------------
// C[M][N] = A[M][K] @ Bt[N][K]^T. If vtout != null, blocks with n0 >= 2560 write
// VT[(b*8+g)*64+d][s] instead of C (fused V transpose).
__global__ __launch_bounds__(256) void gemm_bt2(const unsigned short* __restrict__ A,
                                                const unsigned short* __restrict__ Bt,
                                                void* __restrict__ Cv,
                                                unsigned short* __restrict__ vtout,
                                                int M, int N, int K, int scale_cols,
                                                const int* __restrict__ f32flag) {
  __shared__ unsigned short As[2][128 * 64];
  __shared__ unsigned short Bs[2][128 * 64];
  const int t = threadIdx.x;
  const int lane = t & 63;
  const int wave = t >> 6;
  const int wm = wave >> 1, wn = wave & 1;
  int bx, by;
  {
    const int nx = (int)gridDim.x;
    const int nwg = nx * (int)gridDim.y;
    const int wg = (int)blockIdx.y * nx + (int)blockIdx.x;
    const int cpx = nwg >> 3;
    const int swz = (wg & 7) * cpx + (wg >> 3);
    bx = swz % nx; by = swz / nx;
  }
  const int m0 = by * 128, n0 = bx * 128;
  const int fr = lane & 15;
  const int kb = (lane >> 4) << 4;

  int rowS[4], dofS[4], scS[4];
#pragma unroll
  for (int i = 0; i < 4; ++i) {
    int off = i * 4096 + t * 16;
    dofS[i] = off;
    rowS[i] = off >> 7;
    scS[i]  = (off & 127) ^ ((rowS[i] & 7) << 4);
  }
  const char* pA[4];
  const char* pB[4];
#pragma unroll
  for (int i = 0; i < 4; ++i) {
    pA[i] = (const char*)(A  + (size_t)(m0 + rowS[i]) * K) + scS[i];
    pB[i] = (const char*)(Bt + (size_t)(n0 + rowS[i]) * K) + scS[i];
  }

  f32x4 acc[4][4] = {};
  const int NT = K >> 6;

#pragma unroll
  for (int i = 0; i < 4; ++i) {
    gload16(pA[i], (char*)As[0] + dofS[i]);
    gload16(pB[i], (char*)Bs[0] + dofS[i]);
  }
  __syncthreads();

  for (int kt = 0; kt < NT; ++kt) {
    if (kt + 1 < NT) {
      const int kby = (kt + 1) * 128;
      const int bsel = (kt + 1) & 1;
#pragma unroll
      for (int i = 0; i < 4; ++i) {
        gload16(pA[i] + kby, (char*)As[bsel] + dofS[i]);
        gload16(pB[i] + kby, (char*)Bs[bsel] + dofS[i]);
      }
    }
    const char* Ab = (const char*)As[kt & 1];
    const char* Bb = (const char*)Bs[kt & 1];
#pragma unroll
    for (int ks = 0; ks < 2; ++ks) {
      bf16x8 af[4], bfv[4];
#pragma unroll
      for (int i = 0; i < 4; ++i) {
        const int ra = wm * 64 + i * 16 + fr;
        af[i] = *(const bf16x8*)(Ab + ra * 128 + ((ks * 64 + kb) ^ ((ra & 7) << 4)));
        const int rb = wn * 64 + i * 16 + fr;
        bfv[i] = *(const bf16x8*)(Bb + rb * 128 + ((ks * 64 + kb) ^ ((rb & 7) << 4)));
      }
      __builtin_amdgcn_s_setprio(1);
#pragma unroll
      for (int i = 0; i < 4; ++i)
#pragma unroll
        for (int j = 0; j < 4; ++j)
          acc[i][j] = __builtin_amdgcn_mfma_f32_16x16x32_bf16(af[i], bfv[j], acc[i][j], 0, 0, 0);
      __builtin_amdgcn_s_setprio(0);
    }
    __syncthreads();
  }

  const int cm0 = m0 + wm * 64 + ((lane >> 4) << 2);
  const int cn0 = n0 + wn * 64 + fr;
  if (vtout && n0 >= 2560) {
    const int bb = m0 >> 11;
#pragma unroll
    for (int i = 0; i < 4; ++i) {
      const int s0 = cm0 + i * 16;
#pragma unroll
      for (int j = 0; j < 4; ++j) {
        const int d = cn0 + j * 16 - 2560;
        uint2 pr;
        pr.x = (unsigned int)f2b(acc[i][j][0]) | ((unsigned int)f2b(acc[i][j][1]) << 16);
        pr.y = (unsigned int)f2b(acc[i][j][2]) | ((unsigned int)f2b(acc[i][j][3]) << 16);
        *(uint2*)(vtout + (size_t)(bb * 512 + d) * 2048 + (s0 & 2047)) = pr;
      }
    }
    return;
  }
  const bool of32 = f32flag && (*f32flag != 0);
  if (of32) {
    float* C = (float*)Cv;
#pragma unroll
    for (int i = 0; i < 4; ++i)
#pragma unroll
      for (int j = 0; j < 4; ++j) {
        float sc = (cn0 + j * 16 < scale_cols) ? QSCALE : 1.0f;
#pragma unroll
        for (int r = 0; r < 4; ++r)
          C[(size_t)(cm0 + i * 16 + r) * N + (cn0 + j * 16)] = acc[i][j][r] * sc;
      }
  } else {
    unsigned short* C = (unsigned short*)Cv;
#pragma unroll
    for (int i = 0; i < 4; ++i)
#pragma unroll
      for (int j = 0; j < 4; ++j) {
        float sc = (cn0 + j * 16 < scale_cols) ? QSCALE : 1.0f;
#pragma unroll
        for (int r = 0; r < 4; ++r)
          C[(size_t)(cm0 + i * 16 + r) * N + (cn0 + j * 16)] = f2b(acc[i][j][r] * sc);
      }
  }
}

// ---------------- causal GQA flash attention v7: 1024 blocks, 4-round balanced qt ----------------
__global__ __launch_bounds__(256, 4) void attn_fwd7(const unsigned short* __restrict__ qkv,
                                                    const unsigned short* __restrict__ vt,
                                                    unsigned short* __restrict__ ob) {
  __shared__ unsigned short Ks[2][64 * 64];
  __shared__ unsigned short Vs[2][64 * 64];
  const int t = threadIdx.x, lane = t & 63, w = t >> 6;
  const int half = lane >> 5, q32 = lane & 31;
  const int lin = (int)blockIdx.x;
  const int rr = lin >> 8;
  const int k  = (lin & 255) >> 4;
  const int gb = lin & 15;
  const int g = gb & 7, b = gb >> 3;
  const int qt = (rr == 0) ? 63 - k : (rr == 1) ? 32 + k : (rr == 2) ? 31 - k : k;
  const int h = g * 4 + w;
  const size_t bS = (size_t)b * 2048;
  const size_t vtb = ((size_t)((b << 3) + g)) * 64;
  const int nkt = (qt >> 1) + 1;
  const int q_glob = qt * 32 + q32;

  int rowS[2], dofS[2], cbS[2];
#pragma unroll
  for (int i = 0; i < 2; ++i) {
    int off = i * 4096 + t * 16;
    dofS[i] = off;
    rowS[i] = off >> 7;
    cbS[i]  = (off & 127) ^ ((rowS[i] & 7) << 4);
  }

  bf16x8 qf[4];
  {
    const unsigned short* qrow = qkv + (bS + q_glob) * 3072 + h * 64 + half * 8;
#pragma unroll
    for (int c = 0; c < 4; ++c) qf[c] = *(const bf16x8*)(qrow + 16 * c);
  }
  const unsigned short* kp[2];
  const unsigned short* vp[2];
#pragma unroll
  for (int i = 0; i < 2; ++i) {
    kp[i] = qkv + (bS + rowS[i]) * 3072 + 2048 + g * 64 + (cbS[i] >> 1);
    vp[i] = vt + (vtb + rowS[i]) * 2048 + (cbS[i] >> 1);
  }
  f32x16 Ot0 = {}, Ot1 = {};
  float m_run = -1e30f, l_run = 0.f;

#pragma unroll
  for (int i = 0; i < 2; ++i) {
    gload16(kp[i], (char*)Ks[0] + dofS[i]);
    gload16(vp[i], (char*)Vs[0] + dofS[i]);
    kp[i] += 64 * 3072;
    vp[i] += 64;
  }
  int cur = 0;
  for (int kt = 0; kt < nkt; ++kt) {
    __syncthreads();
    if (kt + 1 < nkt) {
#pragma unroll
      for (int i = 0; i < 2; ++i) {
        gload16(kp[i], (char*)Ks[cur ^ 1] + dofS[i]);
        gload16(vp[i], (char*)Vs[cur ^ 1] + dofS[i]);
        kp[i] += 64 * 3072;
        vp[i] += 64;
      }
    }
    const char* Kb = (const char*)Ks[cur];
    const char* Vb = (const char*)Vs[cur];
    const int sk1 = 2 * kt + 1;
    const bool do1 = (sk1 <= qt);

    f32x16 s0 = {}, s1 = {};
    {
      const int kr0 = q32;
      const int ksw0 = (kr0 & 7) << 4;
      bf16x8 ka0 = *(const bf16x8*)(Kb + kr0 * 128 + ((16 * half) ^ ksw0));
      bf16x8 ka1 = *(const bf16x8*)(Kb + kr0 * 128 + ((32 + 16 * half) ^ ksw0));
      bf16x8 ka2 = *(const bf16x8*)(Kb + kr0 * 128 + ((64 + 16 * half) ^ ksw0));
      bf16x8 ka3 = *(const bf16x8*)(Kb + kr0 * 128 + ((96 + 16 * half) ^ ksw0));
      __builtin_amdgcn_s_setprio(1);
      s0 = __builtin_amdgcn_mfma_f32_32x32x16_bf16(ka0, qf[0], s0, 0, 0, 0);
      s0 = __builtin_amdgcn_mfma_f32_32x32x16_bf16(ka1, qf[1], s0, 0, 0, 0);
      s0 = __builtin_amdgcn_mfma_f32_32x32x16_bf16(ka2, qf[2], s0, 0, 0, 0);
      s0 = __builtin_amdgcn_mfma_f32_32x32x16_bf16(ka3, qf[3], s0, 0, 0, 0);
      __builtin_amdgcn_s_setprio(0);
    }
    if (do1) {
      const int kr1 = 32 + q32;
      const int ksw1 = (kr1 & 7) << 4;
      bf16x8 kb0 = *(const bf16x8*)(Kb + kr1 * 128 + ((16 * half) ^ ksw1));
      bf16x8 kb1 = *(const bf16x8*)(Kb + kr1 * 128 + ((32 + 16 * half) ^ ksw1));
      bf16x8 kb2 = *(const bf16x8*)(Kb + kr1 * 128 + ((64 + 16 * half) ^ ksw1));
      bf16x8 kb3 = *(const bf16x8*)(Kb + kr1 * 128 + ((96 + 16 * half) ^ ksw1));
      __builtin_amdgcn_s_setprio(1);
      s1 = __builtin_amdgcn_mfma_f32_32x32x16_bf16(kb0, qf[0], s1, 0, 0, 0);
      s1 = __builtin_amdgcn_mfma_f32_32x32x16_bf16(kb1, qf[1], s1, 0, 0, 0);
      s1 = __builtin_amdgcn_mfma_f32_32x32x16_bf16(kb2, qf[2], s1, 0, 0, 0);
      s1 = __builtin_amdgcn_mfma_f32_32x32x16_bf16(kb3, qf[3], s1, 0, 0, 0);
      __builtin_amdgcn_s_setprio(0);
    }
    const int qrel = q32 - 4 * half;
    if (2 * kt == qt) {
#pragma unroll
      for (int r = 0; r < 16; ++r) {
        const int pat = (r & 3) + 8 * (r >> 2);
        if (pat > qrel) s0[r] = -1e30f;
      }
    }
    if (do1 && sk1 == qt) {
#pragma unroll
      for (int r = 0; r < 16; ++r) {
        const int pat = (r & 3) + 8 * (r >> 2);
        if (pat > qrel) s1[r] = -1e30f;
      }
    }
    float tm[8];
#pragma unroll
    for (int r = 0; r < 8; ++r) tm[r] = fmaxf(s0[r], s0[r + 8]);
    if (do1) {
#pragma unroll
      for (int r = 0; r < 8; ++r) tm[r] = fmaxf(tm[r], fmaxf(s1[r], s1[r + 8]));
    }
#pragma unroll
    for (int r = 0; r < 4; ++r) tm[r] = fmaxf(tm[r], tm[r + 4]);
    float pm = fmaxf(fmaxf(tm[0], tm[1]), fmaxf(tm[2], tm[3]));
    pm = fmaxf(pm, __shfl_xor(pm, 32, 64));
    if (!__all(pm - m_run <= 8.f)) {
      const float mn = fmaxf(m_run, pm);
      const float corr = fexp2(m_run - mn);
      m_run = mn;
      l_run *= corr;
#pragma unroll
      for (int r = 0; r < 16; ++r) { Ot0[r] *= corr; Ot1[r] *= corr; }
    }
    float ts[8];
#pragma unroll
    for (int r = 0; r < 16; ++r) s0[r] = fexp2(s0[r] - m_run);
    if (do1) {
#pragma unroll
      for (int r = 0; r < 16; ++r) s1[r] = fexp2(s1[r] - m_run);
    }
#pragma unroll
    for (int r = 0; r < 8; ++r) ts[r] = s0[r] + s0[r + 8];
    if (do1) {
#pragma unroll
      for (int r = 0; r < 8; ++r) ts[r] += s1[r] + s1[r + 8];
    }
#pragma unroll
    for (int r = 0; r < 4; ++r) ts[r] += ts[r + 4];
    float rs = (ts[0] + ts[1]) + (ts[2] + ts[3]);
    rs += __shfl_xor(rs, 32, 64);
    l_run += rs;
    bf16x8 pf0, pf1, pf2, pf3;
    {
      unsigned int a01, a23, a45, a67;
      asm("v_cvt_pk_bf16_f32 %0, %1, %2" : "=v"(a01) : "v"(s0[0]), "v"(s0[1]));
      asm("v_cvt_pk_bf16_f32 %0, %1, %2" : "=v"(a23) : "v"(s0[2]), "v"(s0[3]));
      asm("v_cvt_pk_bf16_f32 %0, %1, %2" : "=v"(a45) : "v"(s0[4]), "v"(s0[5]));
      asm("v_cvt_pk_bf16_f32 %0, %1, %2" : "=v"(a67) : "v"(s0[6]), "v"(s0[7]));
      asm("v_permlane32_swap_b32 %0, %1" : "+v"(a01), "+v"(a45));
      asm("v_permlane32_swap_b32 %0, %1" : "+v"(a23), "+v"(a67));
      union { unsigned int u[4]; bf16x8 v; } fu;
      fu.u[0] = a01; fu.u[1] = a23; fu.u[2] = a45; fu.u[3] = a67;
      pf0 = fu.v;
      asm("v_cvt_pk_bf16_f32 %0, %1, %2" : "=v"(a01) : "v"(s0[8]),  "v"(s0[9]));
      asm("v_cvt_pk_bf16_f32 %0, %1, %2" : "=v"(a23) : "v"(s0[10]), "v"(s0[11]));
      asm("v_cvt_pk_bf16_f32 %0, %1, %2" : "=v"(a45) : "v"(s0[12]), "v"(s0[13]));
      asm("v_cvt_pk_bf16_f32 %0, %1, %2" : "=v"(a67) : "v"(s0[14]), "v"(s0[15]));
      asm("v_permlane32_swap_b32 %0, %1" : "+v"(a01), "+v"(a45));
      asm("v_permlane32_swap_b32 %0, %1" : "+v"(a23), "+v"(a67));
      fu.u[0] = a01; fu.u[1] = a23; fu.u[2] = a45; fu.u[3] = a67;
      pf1 = fu.v;
    }
    if (do1) {
      unsigned int a01, a23, a45, a67;
      asm("v_cvt_pk_bf16_f32 %0, %1, %2" : "=v"(a01) : "v"(s1[0]), "v"(s1[1]));
      asm("v_cvt_pk_bf16_f32 %0, %1, %2" : "=v"(a23) : "v"(s1[2]), "v"(s1[3]));
      asm("v_cvt_pk_bf16_f32 %0, %1, %2" : "=v"(a45) : "v"(s1[4]), "v"(s1[5]));
      asm("v_cvt_pk_bf16_f32 %0, %1, %2" : "=v"(a67) : "v"(s1[6]), "v"(s1[7]));
      asm("v_permlane32_swap_b32 %0, %1" : "+v"(a01), "+v"(a45));
      asm("v_permlane32_swap_b32 %0, %1" : "+v"(a23), "+v"(a67));
      union { unsigned int u[4]; bf16x8 v; } fu;
      fu.u[0] = a01; fu.u[1] = a23; fu.u[2] = a45; fu.u[3] = a67;
      pf2 = fu.v;
      asm("v_cvt_pk_bf16_f32 %0, %1, %2" : "=v"(a01) : "v"(s1[8]),  "v"(s1[9]));
      asm("v_cvt_pk_bf16_f32 %0, %1, %2" : "=v"(a23) : "v"(s1[10]), "v"(s1[11]));
      asm("v_cvt_pk_bf16_f32 %0, %1, %2" : "=v"(a45) : "v"(s1[12]), "v"(s1[13]));
      asm("v_cvt_pk_bf16_f32 %0, %1, %2" : "=v"(a67) : "v"(s1[14]), "v"(s1[15]));
      asm("v_permlane32_swap_b32 %0, %1" : "+v"(a01), "+v"(a45));
      asm("v_permlane32_swap_b32 %0, %1" : "+v"(a23), "+v"(a67));
      fu.u[0] = a01; fu.u[1] = a23; fu.u[2] = a45; fu.u[3] = a67;
      pf3 = fu.v;
    }
    const int vsw0 = (q32 & 7) << 4;
    {
      const int cbase = 16 * half;
      bf16x8 vf00 = *(const bf16x8*)(Vb + q32 * 128 + (cbase ^ vsw0));
      bf16x8 vf01 = *(const bf16x8*)(Vb + q32 * 128 + ((cbase + 32) ^ vsw0));
      bf16x8 vf10 = *(const bf16x8*)(Vb + (32 + q32) * 128 + (cbase ^ vsw0));
      bf16x8 vf11 = *(const bf16x8*)(Vb + (32 + q32) * 128 + ((cbase + 32) ^ vsw0));
      __builtin_amdgcn_s_setprio(1);
      Ot0 = __builtin_amdgcn_mfma_f32_32x32x16_bf16(vf00, pf0, Ot0, 0, 0, 0);
      Ot0 = __builtin_amdgcn_mfma_f32_32x32x16_bf16(vf01, pf1, Ot0, 0, 0, 0);
      Ot1 = __builtin_amdgcn_mfma_f32_32x32x16_bf16(vf10, pf0, Ot1, 0, 0, 0);
      Ot1 = __builtin_amdgcn_mfma_f32_32x32x16_bf16(vf11, pf1, Ot1, 0, 0, 0);
      __builtin_amdgcn_s_setprio(0);
    }
    if (do1) {
      const int cbase = 64 + 16 * half;
      bf16x8 vf00 = *(const bf16x8*)(Vb + q32 * 128 + (cbase ^ vsw0));
      bf16x8 vf01 = *(const bf16x8*)(Vb + q32 * 128 + ((cbase + 32) ^ vsw0));
      bf16x8 vf10 = *(const bf16x8*)(Vb + (32 + q32) * 128 + (cbase ^ vsw0));
      bf16x8 vf11 = *(const bf16x8*)(Vb + (32 + q32) * 128 + ((cbase + 32) ^ vsw0));
      __builtin_amdgcn_s_setprio(1);
      Ot0 = __builtin_amdgcn_mfma_f32_32x32x16_bf16(vf00, pf2, Ot0, 0, 0, 0);
      Ot0 = __builtin_amdgcn_mfma_f32_32x32x16_bf16(vf01, pf3, Ot0, 0, 0, 0);
      Ot1 = __builtin_amdgcn_mfma_f32_32x32x16_bf16(vf10, pf2, Ot1, 0, 0, 0);
      Ot1 = __builtin_amdgcn_mfma_f32_32x32x16_bf16(vf11, pf3, Ot1, 0, 0, 0);
      __builtin_amdgcn_s_setprio(0);
    }
    cur ^= 1;
  }
  const float inv = 1.f / l_run;
  unsigned short* orow = ob + (bS + q_glob) * 2048 + h * 64;
#pragma unroll
  for (int j = 0; j < 4; ++j) {
    uint2 pr;
    pr.x = (unsigned int)f2b(Ot0[4 * j + 0] * inv) | ((unsigned int)f2b(Ot0[4 * j + 1] * inv) << 16);
    pr.y = (unsigned int)f2b(Ot0[4 * j + 2] * inv) | ((unsigned int)f2b(Ot0[4 * j + 3] * inv) << 16);
    *(uint2*)(orow + 8 * j + 4 * half) = pr;
    uint2 pr2;
    pr2.x = (unsigned int)f2b(Ot1[4 * j + 0] * inv) | ((unsigned int)f2b(Ot1[4 * j + 1] * inv) << 16);
    pr2.y = (unsigned int)f2b(Ot1[4 * j + 2] * inv) | ((unsigned int)f2b(Ot1[4 * j + 3] * inv) << 16);
    *(uint2*)(orow + 32 + 8 * j + 4 * half) = pr2;
  }
}

extern "C" void kernel_launch(void* const* d_in, const int* in_sizes, int n_in,
                              void* d_out, int out_size, void* d_ws, size_t ws_size,
                              hipStream_t stream) {
  (void)in_sizes; (void)n_in; (void)out_size; (void)ws_size;
  const void* x  = d_in[0];
  const void* wq = d_in[1];
  const void* wk = d_in[2];
  const void* wv = d_in[3];
  const void* wo = d_in[4];
  unsigned short* ws = (unsigned short*)d_ws;

  int* FLAG = (int*)ws;
  unsigned short* WT  = ws + 128;
  unsigned short* WOT = WT  + (size_t)3072 * 2048;
  unsigned short* QKV = WOT + (size_t)2048 * 2048;
  unsigned short* VT  = QKV + (size_t)4096 * 3072;
  unsigned short* OB  = VT  + (size_t)16 * 64 * 2048;
  unsigned short* XB  = OB;  // x-as-bf16 (disjoint lifetime vs OB)

  detect_dtype<<<1, 64, 0, stream>>>((const unsigned short*)x, FLAG);
  transpose_w4<<<dim3(32, 32, 4), 256, 0, stream>>>(wq, wk, wv, wo, WT, WOT, FLAG);
  convert_x<<<4096, 256, 0, stream>>>(x, XB, FLAG);

  // QKV projection (proven 128^2 kernel); V columns written directly as VT
  gemm_bt2<<<dim3(24, 32), 256, 0, stream>>>(XB, WT, QKV, VT, 4096, 3072, 2048, 2048, nullptr);
  attn_fwd7<<<dim3(1024), 256, 0, stream>>>(QKV, VT, OB);
  gemm_bt2<<<dim3(16, 32), 256, 0, stream>>>(OB, WOT, d_out, nullptr, 4096, 2048, 2048, 0, FLAG);
}